// Round 1
// baseline (816.576 us; speedup 1.0000x reference)
//
#include <hip/hip_runtime.h>
#include <cstdint>

constexpr int NG = 64;     // graphs
constexpr int H  = 256;    // hidden width

// ---------- degree histogram over real edges ----------
__global__ void hist_kernel(const int* __restrict__ dst, int* __restrict__ cnt, int E) {
    int e = blockIdx.x * blockDim.x + threadIdx.x;
    if (e < E) atomicAdd(&cnt[dst[e]], 1);
}

// dinv = rsqrt(in_deg + 1)   (self-loop included)
__global__ void dinv_kernel(const int* __restrict__ cnt, float* __restrict__ dinv, int n) {
    int i = blockIdx.x * blockDim.x + threadIdx.x;
    if (i < n) dinv[i] = rsqrtf((float)(cnt[i] + 1));
}

// ---------- single-block exclusive scan (CSR row pointers) ----------
__global__ __launch_bounds__(1024) void scan_kernel(const int* __restrict__ cnt,
                                                    int* __restrict__ row_ptr,
                                                    int* __restrict__ fill, int n) {
    __shared__ int buf[1024];
    __shared__ int carry_s;
    int t = threadIdx.x;
    if (t == 0) carry_s = 0;
    __syncthreads();
    for (int base = 0; base < n; base += 1024) {
        int i = base + t;
        int v = (i < n) ? cnt[i] : 0;
        buf[t] = v;
        __syncthreads();
        for (int off = 1; off < 1024; off <<= 1) {
            int add = (t >= off) ? buf[t - off] : 0;
            __syncthreads();
            buf[t] += add;
            __syncthreads();
        }
        int incl  = buf[t];
        int carry = carry_s;
        int excl  = carry + incl - v;
        if (i < n) { row_ptr[i] = excl; fill[i] = excl; }
        __syncthreads();
        if (t == 1023) carry_s = carry + incl;
        __syncthreads();
    }
    if (t == 0) row_ptr[n] = carry_s;
}

// ---------- counting-sort edges by dst ----------
__global__ void scatter_kernel(const int* __restrict__ src, const int* __restrict__ dst,
                               int* __restrict__ fill, int* __restrict__ ssrc, int E) {
    int e = blockIdx.x * blockDim.x + threadIdx.x;
    if (e < E) {
        int pos = atomicAdd(&fill[dst[e]], 1);
        ssrc[pos] = src[e];
    }
}

// ---------- y0 = dinv ⊙ x  (width 128) ----------
__global__ void prescale_kernel(const float* __restrict__ x, const float* __restrict__ dinv,
                                float* __restrict__ y, int total /* N*128 floats */) {
    int idx = blockIdx.x * blockDim.x + threadIdx.x;   // float4 index
    int f = idx * 4;
    if (f >= total) return;
    float dv = dinv[f >> 7];
    float4 v = *reinterpret_cast<const float4*>(x + f);
    v.x *= dv; v.y *= dv; v.z *= dv; v.w *= dv;
    *reinterpret_cast<float4*>(y + f) = v;
}

// ---------- z[i] = dinv[i]*(y[i] + sum_{src in N(i)} y[src]) ----------
// one wave per node; lane holds VEC consecutive floats
template<int VEC>
__global__ __launch_bounds__(256) void agg_kernel(const float* __restrict__ y,
                                                  const float* __restrict__ dinv,
                                                  const int* __restrict__ row_ptr,
                                                  const int* __restrict__ ssrc,
                                                  float* __restrict__ z, int n) {
    constexpr int W = VEC * 64;
    int wave = threadIdx.x >> 6;
    int lane = threadIdx.x & 63;
    int node = blockIdx.x * 4 + wave;
    if (node >= n) return;
    float acc[VEC];
    {
        const float* yr = y + (size_t)node * W + lane * VEC;
        if constexpr (VEC == 4) {
            float4 v = *reinterpret_cast<const float4*>(yr);
            acc[0] = v.x; acc[1] = v.y; acc[2] = v.z; acc[3] = v.w;
        } else {
            float2 v = *reinterpret_cast<const float2*>(yr);
            acc[0] = v.x; acc[1] = v.y;
        }
    }
    int beg = row_ptr[node], end = row_ptr[node + 1];
    for (int e = beg; e < end; ++e) {
        int s = ssrc[e];
        const float* ys = y + (size_t)s * W + lane * VEC;
        if constexpr (VEC == 4) {
            float4 v = *reinterpret_cast<const float4*>(ys);
            acc[0] += v.x; acc[1] += v.y; acc[2] += v.z; acc[3] += v.w;
        } else {
            float2 v = *reinterpret_cast<const float2*>(ys);
            acc[0] += v.x; acc[1] += v.y;
        }
    }
    float dv = dinv[node];
    float* zr = z + (size_t)node * W + lane * VEC;
    if constexpr (VEC == 4) {
        float4 o; o.x = dv*acc[0]; o.y = dv*acc[1]; o.z = dv*acc[2]; o.w = dv*acc[3];
        *reinterpret_cast<float4*>(zr) = o;
    } else {
        float2 o; o.x = dv*acc[0]; o.y = dv*acc[1];
        *reinterpret_cast<float2*>(zr) = o;
    }
}

// ---------- C = dinv ⊙ relu(A@W + b), A:[M,K], W:[K,256], C:[M,256] ----------
template<bool RELU, bool SCALE>
__global__ __launch_bounds__(256) void gemm_kernel(const float* __restrict__ A,
                                                   const float* __restrict__ Wm,
                                                   const float* __restrict__ bias,
                                                   const float* __restrict__ dinv,
                                                   float* __restrict__ C, int M, int K) {
    constexpr int BM = 64, BN = 64, BK = 32;
    __shared__ float As[BK][BM + 4];   // k-major, padded for store conflicts + b128 alignment
    __shared__ float Bs[BK][BN];
    const int tid = threadIdx.x;
    const int bm = blockIdx.x * BM;
    const int bn = blockIdx.y * BN;
    const int tr = tid >> 4;   // 0..15
    const int tc = tid & 15;   // 0..15
    float acc[4][4] = {};
    for (int k0 = 0; k0 < K; k0 += BK) {
        #pragma unroll
        for (int i = tid; i < (BM * BK) / 4; i += 256) {
            int r = i >> 3;            // (i*4)/32
            int c = (i & 7) << 2;      // (i*4)%32
            float4 v = make_float4(0.f, 0.f, 0.f, 0.f);
            int grow = bm + r;
            if (grow < M) v = *reinterpret_cast<const float4*>(A + (size_t)grow * K + k0 + c);
            As[c + 0][r] = v.x; As[c + 1][r] = v.y; As[c + 2][r] = v.z; As[c + 3][r] = v.w;
        }
        #pragma unroll
        for (int i = tid; i < (BK * BN) / 4; i += 256) {
            int r = i >> 4;            // (i*4)/64
            int c = (i & 15) << 2;
            *reinterpret_cast<float4*>(&Bs[r][c]) =
                *reinterpret_cast<const float4*>(Wm + (size_t)(k0 + r) * H + bn + c);
        }
        __syncthreads();
        #pragma unroll
        for (int kk = 0; kk < BK; ++kk) {
            float4 a = *reinterpret_cast<const float4*>(&As[kk][tr * 4]);
            float4 b = *reinterpret_cast<const float4*>(&Bs[kk][tc * 4]);
            float av[4] = {a.x, a.y, a.z, a.w};
            float bv[4] = {b.x, b.y, b.z, b.w};
            #pragma unroll
            for (int i = 0; i < 4; ++i)
                #pragma unroll
                for (int j = 0; j < 4; ++j)
                    acc[i][j] += av[i] * bv[j];
        }
        __syncthreads();
    }
    float4 bvals = *reinterpret_cast<const float4*>(bias + bn + tc * 4);
    float bb[4] = {bvals.x, bvals.y, bvals.z, bvals.w};
    #pragma unroll
    for (int i = 0; i < 4; ++i) {
        int row = bm + tr * 4 + i;
        if (row >= M) continue;
        float dv = SCALE ? dinv[row] : 1.f;
        float t0 = acc[i][0] + bb[0], t1 = acc[i][1] + bb[1];
        float t2 = acc[i][2] + bb[2], t3 = acc[i][3] + bb[3];
        if (RELU) { t0 = fmaxf(t0, 0.f); t1 = fmaxf(t1, 0.f); t2 = fmaxf(t2, 0.f); t3 = fmaxf(t3, 0.f); }
        float4 o; o.x = t0 * dv; o.y = t1 * dv; o.z = t2 * dv; o.w = t3 * dv;
        *reinterpret_cast<float4*>(C + (size_t)row * H + bn + tc * 4) = o;
    }
}

// ---------- mean-pool partials: batch is sorted, flush at graph boundaries ----------
__global__ __launch_bounds__(256) void pool_kernel(const float* __restrict__ z,
                                                   const int* __restrict__ batch,
                                                   float* __restrict__ sums,
                                                   int* __restrict__ gcnt, int n) {
    constexpr int NCH = 128;
    int t = threadIdx.x;             // feature
    int base = blockIdx.x * NCH;
    if (base >= n) return;
    int endn = min(base + NCH, n);
    int cur = batch[base];
    float local = 0.f;
    int cl = 0;
    for (int i = base; i < endn; ++i) {
        int g = batch[i];
        if (g != cur) {
            atomicAdd(&sums[cur * H + t], local);
            if (t == 0) atomicAdd(&gcnt[cur], cl);
            local = 0.f; cl = 0; cur = g;
        }
        local += z[(size_t)i * H + t];
        cl++;
    }
    atomicAdd(&sums[cur * H + t], local);
    if (t == 0) atomicAdd(&gcnt[cur], cl);
}

// ---------- head: pooled = sums/cnt; out = ((pooled@W3+b3)@L1+b)@L2+b ----------
__global__ __launch_bounds__(256) void head_kernel(const float* __restrict__ sums,
                                                   const int* __restrict__ gcnt,
                                                   const float* __restrict__ w3, const float* __restrict__ b3,
                                                   const float* __restrict__ l1w, const float* __restrict__ l1b,
                                                   const float* __restrict__ l2w, const float* __restrict__ l2b,
                                                   float* __restrict__ out) {
    __shared__ float pooled[H];
    __shared__ float t3[H];
    __shared__ float mid[H / 2];
    int g = blockIdx.x, t = threadIdx.x;
    float c = (float)max(gcnt[g], 1);
    pooled[t] = sums[g * H + t] / c;
    __syncthreads();
    float a = b3[t];
    for (int k = 0; k < H; ++k) a += pooled[k] * w3[k * H + t];
    t3[t] = a;
    __syncthreads();
    if (t < H / 2) {
        float m = l1b[t];
        for (int k = 0; k < H; ++k) m += t3[k] * l1w[k * (H / 2) + t];
        mid[t] = m;
    }
    __syncthreads();
    if (t < 3) {
        float o = l2b[t];
        for (int k = 0; k < H / 2; ++k) o += mid[k] * l2w[k * 3 + t];
        out[g * 3 + t] = o;
    }
}

extern "C" void kernel_launch(void* const* d_in, const int* in_sizes, int n_in,
                              void* d_out, int out_size, void* d_ws, size_t ws_size,
                              hipStream_t stream) {
    const float* x   = (const float*)d_in[0];
    const int*   ei  = (const int*)d_in[2];     // [2,E]: src then dst
    const int*   bat = (const int*)d_in[3];
    const float* w1  = (const float*)d_in[4];
    const float* b1  = (const float*)d_in[5];
    const float* w2  = (const float*)d_in[6];
    const float* b2  = (const float*)d_in[7];
    const float* w3  = (const float*)d_in[8];
    const float* b3  = (const float*)d_in[9];
    const float* l1w = (const float*)d_in[10];
    const float* l1b = (const float*)d_in[11];
    const float* l2w = (const float*)d_in[12];
    const float* l2b = (const float*)d_in[13];
    float* out = (float*)d_out;

    const int N = in_sizes[0] / 128;   // 50000
    const int E = in_sizes[2] / 2;     // 800000

    char* ws = (char*)d_ws;
    size_t off = 0;
    auto alloc = [&](size_t bytes) {
        void* p = ws + off;
        off = (off + bytes + 255) & ~(size_t)255;
        return p;
    };
    float* NB0     = (float*)alloc((size_t)N * H * 4);
    float* NB1     = (float*)alloc((size_t)N * H * 4);
    int*   cnt     = (int*)alloc((size_t)N * 4);
    float* dinv    = (float*)alloc((size_t)N * 4);
    int*   row_ptr = (int*)alloc((size_t)(N + 1) * 4);
    int*   fill    = (int*)alloc((size_t)N * 4);
    int*   ssrc    = (int*)alloc((size_t)E * 4);
    float* sums    = (float*)alloc((size_t)NG * H * 4);
    int*   gcnt    = (int*)alloc((size_t)NG * 4);

    hipMemsetAsync(cnt, 0, (size_t)N * 4, stream);
    hipMemsetAsync(sums, 0, (size_t)NG * H * 4, stream);
    hipMemsetAsync(gcnt, 0, (size_t)NG * 4, stream);

    hist_kernel<<<(E + 255) / 256, 256, 0, stream>>>(ei + E, cnt, E);
    dinv_kernel<<<(N + 255) / 256, 256, 0, stream>>>(cnt, dinv, N);
    scan_kernel<<<1, 1024, 0, stream>>>(cnt, row_ptr, fill, N);
    scatter_kernel<<<(E + 255) / 256, 256, 0, stream>>>(ei, ei + E, fill, ssrc, E);

    // layer 1: aggregate x (width 128) then GEMM 128->256
    prescale_kernel<<<(N * 128 / 4 + 255) / 256, 256, 0, stream>>>(x, dinv, NB0, N * 128);
    agg_kernel<2><<<(N + 3) / 4, 256, 0, stream>>>(NB0, dinv, row_ptr, ssrc, NB1, N);
    gemm_kernel<true, true><<<dim3((N + 63) / 64, 4), 256, 0, stream>>>(NB1, w1, b1, dinv, NB0, N, 128);

    // layer 2
    agg_kernel<4><<<(N + 3) / 4, 256, 0, stream>>>(NB0, dinv, row_ptr, ssrc, NB1, N);
    gemm_kernel<true, true><<<dim3((N + 63) / 64, 4), 256, 0, stream>>>(NB1, w2, b2, dinv, NB0, N, 256);

    // layer 3: aggregate only; W3 folds into the head (pool commutes with linear, no relu)
    agg_kernel<4><<<(N + 3) / 4, 256, 0, stream>>>(NB0, dinv, row_ptr, ssrc, NB1, N);

    pool_kernel<<<(N + 127) / 128, 256, 0, stream>>>(NB1, bat, sums, gcnt, N);
    head_kernel<<<NG, 256, 0, stream>>>(sums, gcnt, w3, b3, l1w, l1b, l2w, l2b, out);
}

// Round 2
// 553.796 us; speedup vs baseline: 1.4745x; 1.4745x over previous
//
#include <hip/hip_runtime.h>
#include <cstdint>

constexpr int NG = 64;     // graphs
constexpr int H  = 256;    // hidden width

// ---------- bf16 helpers (RNE pack, bit-shift unpack) ----------
__device__ __forceinline__ uint32_t pk_bf16(float a, float b) {
    uint32_t ua = __builtin_bit_cast(uint32_t, a);
    uint32_t ub = __builtin_bit_cast(uint32_t, b);
    ua += 0x7fffu + ((ua >> 16) & 1u);
    ub += 0x7fffu + ((ub >> 16) & 1u);
    return (ua >> 16) | (ub & 0xffff0000u);
}
__device__ __forceinline__ void bf2acc(uint32_t u, float& a0, float& a1) {
    a0 += __builtin_bit_cast(float, u << 16);
    a1 += __builtin_bit_cast(float, u & 0xffff0000u);
}

// ---------- degree histogram over real edges ----------
__global__ void hist_kernel(const int* __restrict__ dst, int* __restrict__ cnt, int E) {
    int e = blockIdx.x * blockDim.x + threadIdx.x;
    if (e < E) atomicAdd(&cnt[dst[e]], 1);
}

// dinv = rsqrt(in_deg + 1)   (self-loop included)
__global__ void dinv_kernel(const int* __restrict__ cnt, float* __restrict__ dinv, int n) {
    int i = blockIdx.x * blockDim.x + threadIdx.x;
    if (i < n) dinv[i] = rsqrtf((float)(cnt[i] + 1));
}

// ---------- hierarchical exclusive scan: A (block sums) -> B (scan sums) -> C (per-node) ----------
__global__ __launch_bounds__(256) void scanA(const int* __restrict__ cnt, int* __restrict__ bsum, int n) {
    __shared__ int sh[256];
    int t = threadIdx.x, i = blockIdx.x * 256 + t;
    sh[t] = (i < n) ? cnt[i] : 0;
    __syncthreads();
    for (int off = 128; off > 0; off >>= 1) {
        if (t < off) sh[t] += sh[t + off];
        __syncthreads();
    }
    if (t == 0) bsum[blockIdx.x] = sh[0];
}

__global__ __launch_bounds__(256) void scanB(const int* __restrict__ bsum, int* __restrict__ boff,
                                             int* __restrict__ total_out, int nb) {
    __shared__ int sh[256];
    int t = threadIdx.x;
    int v = (t < nb) ? bsum[t] : 0;
    sh[t] = v;
    __syncthreads();
    for (int off = 1; off < 256; off <<= 1) {
        int a = (t >= off) ? sh[t - off] : 0;
        __syncthreads();
        sh[t] += a;
        __syncthreads();
    }
    if (t < nb) boff[t] = sh[t] - v;
    if (t == nb - 1) *total_out = sh[t];
}

__global__ __launch_bounds__(256) void scanC(const int* __restrict__ cnt, const int* __restrict__ boff,
                                             int* __restrict__ row_ptr, int* __restrict__ fill, int n) {
    __shared__ int sh[256];
    int t = threadIdx.x, i = blockIdx.x * 256 + t;
    int v = (i < n) ? cnt[i] : 0;
    sh[t] = v;
    __syncthreads();
    for (int off = 1; off < 256; off <<= 1) {
        int a = (t >= off) ? sh[t - off] : 0;
        __syncthreads();
        sh[t] += a;
        __syncthreads();
    }
    if (i < n) {
        int excl = boff[blockIdx.x] + sh[t] - v;
        row_ptr[i] = excl;
        fill[i] = excl;
    }
}

// ---------- counting-sort edges by dst ----------
__global__ void scatter_kernel(const int* __restrict__ src, const int* __restrict__ dst,
                               int* __restrict__ fill, int* __restrict__ ssrc, int E) {
    int e = blockIdx.x * blockDim.x + threadIdx.x;
    if (e < E) {
        int pos = atomicAdd(&fill[dst[e]], 1);
        ssrc[pos] = src[e];
    }
}

// ---------- y0 = bf16(dinv ⊙ x)  (width 128) ----------
__global__ void prescale_kernel(const float* __restrict__ x, const float* __restrict__ dinv,
                                ushort* __restrict__ y, int total /* N*128 floats */) {
    int idx = blockIdx.x * blockDim.x + threadIdx.x;   // float4 index
    int f = idx * 4;
    if (f >= total) return;
    float dv = dinv[f >> 7];
    float4 v = *reinterpret_cast<const float4*>(x + f);
    uint2 o;
    o.x = pk_bf16(v.x * dv, v.y * dv);
    o.y = pk_bf16(v.z * dv, v.w * dv);
    *reinterpret_cast<uint2*>(y + f) = o;
}

// ---------- z[i] = dinv[i]*(y[i] + sum_{src in N(i)} y[src]), y bf16, z f32 ----------
// one wave per node; lane holds VEC consecutive bf16; 4x edge unroll for MLP
template<int VEC>
__global__ __launch_bounds__(256) void agg_kernel(const ushort* __restrict__ y,
                                                  const float* __restrict__ dinv,
                                                  const int* __restrict__ row_ptr,
                                                  const int* __restrict__ ssrc,
                                                  float* __restrict__ z, int n) {
    constexpr int W = VEC * 64;
    int wave = threadIdx.x >> 6;
    int lane = threadIdx.x & 63;
    int node = blockIdx.x * 4 + wave;
    if (node >= n) return;
    float acc[VEC] = {};

    auto ld4 = [&](int s) -> uint2 {
        return *reinterpret_cast<const uint2*>(y + (size_t)s * W + lane * VEC);
    };
    auto ld2 = [&](int s) -> uint32_t {
        return *reinterpret_cast<const uint32_t*>(y + (size_t)s * W + lane * VEC);
    };

    // self term
    if constexpr (VEC == 4) {
        uint2 v = ld4(node);
        bf2acc(v.x, acc[0], acc[1]); bf2acc(v.y, acc[2], acc[3]);
    } else {
        bf2acc(ld2(node), acc[0], acc[1]);
    }

    int beg = row_ptr[node], end = row_ptr[node + 1];
    int e = beg;
    for (; e + 4 <= end; e += 4) {
        int s0 = ssrc[e], s1 = ssrc[e + 1], s2 = ssrc[e + 2], s3 = ssrc[e + 3];
        if constexpr (VEC == 4) {
            uint2 v0 = ld4(s0), v1 = ld4(s1), v2 = ld4(s2), v3 = ld4(s3);
            bf2acc(v0.x, acc[0], acc[1]); bf2acc(v0.y, acc[2], acc[3]);
            bf2acc(v1.x, acc[0], acc[1]); bf2acc(v1.y, acc[2], acc[3]);
            bf2acc(v2.x, acc[0], acc[1]); bf2acc(v2.y, acc[2], acc[3]);
            bf2acc(v3.x, acc[0], acc[1]); bf2acc(v3.y, acc[2], acc[3]);
        } else {
            uint32_t v0 = ld2(s0), v1 = ld2(s1), v2 = ld2(s2), v3 = ld2(s3);
            bf2acc(v0, acc[0], acc[1]); bf2acc(v1, acc[0], acc[1]);
            bf2acc(v2, acc[0], acc[1]); bf2acc(v3, acc[0], acc[1]);
        }
    }
    for (; e < end; ++e) {
        if constexpr (VEC == 4) {
            uint2 v = ld4(ssrc[e]);
            bf2acc(v.x, acc[0], acc[1]); bf2acc(v.y, acc[2], acc[3]);
        } else {
            bf2acc(ld2(ssrc[e]), acc[0], acc[1]);
        }
    }

    float dv = dinv[node];
    float* zr = z + (size_t)node * W + lane * VEC;
    if constexpr (VEC == 4) {
        float4 o; o.x = dv * acc[0]; o.y = dv * acc[1]; o.z = dv * acc[2]; o.w = dv * acc[3];
        *reinterpret_cast<float4*>(zr) = o;
    } else {
        float2 o; o.x = dv * acc[0]; o.y = dv * acc[1];
        *reinterpret_cast<float2*>(zr) = o;
    }
}

// ---------- C = bf16(dinv ⊙ relu(A@W + b)), A:[M,K] f32, W:[K,256], C:[M,256] bf16 ----------
template<bool RELU>
__global__ __launch_bounds__(256) void gemm_kernel(const float* __restrict__ A,
                                                   const float* __restrict__ Wm,
                                                   const float* __restrict__ bias,
                                                   const float* __restrict__ dinv,
                                                   ushort* __restrict__ C, int M, int K) {
    constexpr int BM = 64, BN = 64, BK = 32;
    __shared__ float As[BK][BM + 4];   // k-major
    __shared__ float Bs[BK][BN];
    const int tid = threadIdx.x;
    const int bm = blockIdx.x * BM;
    const int bn = blockIdx.y * BN;
    const int tr = tid >> 4;   // 0..15
    const int tc = tid & 15;   // 0..15
    float acc[4][4] = {};
    for (int k0 = 0; k0 < K; k0 += BK) {
        #pragma unroll
        for (int i = tid; i < (BM * BK) / 4; i += 256) {
            int r = i >> 3;
            int c = (i & 7) << 2;
            float4 v = make_float4(0.f, 0.f, 0.f, 0.f);
            int grow = bm + r;
            if (grow < M) v = *reinterpret_cast<const float4*>(A + (size_t)grow * K + k0 + c);
            As[c + 0][r] = v.x; As[c + 1][r] = v.y; As[c + 2][r] = v.z; As[c + 3][r] = v.w;
        }
        #pragma unroll
        for (int i = tid; i < (BK * BN) / 4; i += 256) {
            int r = i >> 4;
            int c = (i & 15) << 2;
            *reinterpret_cast<float4*>(&Bs[r][c]) =
                *reinterpret_cast<const float4*>(Wm + (size_t)(k0 + r) * H + bn + c);
        }
        __syncthreads();
        #pragma unroll
        for (int kk = 0; kk < BK; ++kk) {
            float4 a = *reinterpret_cast<const float4*>(&As[kk][tr * 4]);
            float4 b = *reinterpret_cast<const float4*>(&Bs[kk][tc * 4]);
            float av[4] = {a.x, a.y, a.z, a.w};
            float bv[4] = {b.x, b.y, b.z, b.w};
            #pragma unroll
            for (int i = 0; i < 4; ++i)
                #pragma unroll
                for (int j = 0; j < 4; ++j)
                    acc[i][j] += av[i] * bv[j];
        }
        __syncthreads();
    }
    float4 bvals = *reinterpret_cast<const float4*>(bias + bn + tc * 4);
    float bb[4] = {bvals.x, bvals.y, bvals.z, bvals.w};
    #pragma unroll
    for (int i = 0; i < 4; ++i) {
        int row = bm + tr * 4 + i;
        if (row >= M) continue;
        float dv = dinv[row];
        float t0 = acc[i][0] + bb[0], t1 = acc[i][1] + bb[1];
        float t2 = acc[i][2] + bb[2], t3 = acc[i][3] + bb[3];
        if (RELU) { t0 = fmaxf(t0, 0.f); t1 = fmaxf(t1, 0.f); t2 = fmaxf(t2, 0.f); t3 = fmaxf(t3, 0.f); }
        uint2 o;
        o.x = pk_bf16(t0 * dv, t1 * dv);
        o.y = pk_bf16(t2 * dv, t3 * dv);
        *reinterpret_cast<uint2*>(C + (size_t)row * H + bn + tc * 4) = o;
    }
}

// ---------- mean-pool partials: batch is sorted, flush at graph boundaries ----------
__global__ __launch_bounds__(256) void pool_kernel(const float* __restrict__ z,
                                                   const int* __restrict__ batch,
                                                   float* __restrict__ sums,
                                                   int* __restrict__ gcnt, int n) {
    constexpr int NCH = 128;
    int t = threadIdx.x;             // feature
    int base = blockIdx.x * NCH;
    if (base >= n) return;
    int endn = min(base + NCH, n);
    int cur = batch[base];
    float local = 0.f;
    int cl = 0;
    for (int i = base; i < endn; ++i) {
        int g = batch[i];
        if (g != cur) {
            atomicAdd(&sums[cur * H + t], local);
            if (t == 0) atomicAdd(&gcnt[cur], cl);
            local = 0.f; cl = 0; cur = g;
        }
        local += z[(size_t)i * H + t];
        cl++;
    }
    atomicAdd(&sums[cur * H + t], local);
    if (t == 0) atomicAdd(&gcnt[cur], cl);
}

// ---------- head: pooled = sums/cnt; out = ((pooled@W3+b3)@L1+b)@L2+b ----------
__global__ __launch_bounds__(256) void head_kernel(const float* __restrict__ sums,
                                                   const int* __restrict__ gcnt,
                                                   const float* __restrict__ w3, const float* __restrict__ b3,
                                                   const float* __restrict__ l1w, const float* __restrict__ l1b,
                                                   const float* __restrict__ l2w, const float* __restrict__ l2b,
                                                   float* __restrict__ out) {
    __shared__ float pooled[H];
    __shared__ float t3[H];
    __shared__ float mid[H / 2];
    int g = blockIdx.x, t = threadIdx.x;
    float c = (float)max(gcnt[g], 1);
    pooled[t] = sums[g * H + t] / c;
    __syncthreads();
    float a = b3[t];
    for (int k = 0; k < H; ++k) a += pooled[k] * w3[k * H + t];
    t3[t] = a;
    __syncthreads();
    if (t < H / 2) {
        float m = l1b[t];
        for (int k = 0; k < H; ++k) m += t3[k] * l1w[k * (H / 2) + t];
        mid[t] = m;
    }
    __syncthreads();
    if (t < 3) {
        float o = l2b[t];
        for (int k = 0; k < H / 2; ++k) o += mid[k] * l2w[k * 3 + t];
        out[g * 3 + t] = o;
    }
}

extern "C" void kernel_launch(void* const* d_in, const int* in_sizes, int n_in,
                              void* d_out, int out_size, void* d_ws, size_t ws_size,
                              hipStream_t stream) {
    const float* x   = (const float*)d_in[0];
    const int*   ei  = (const int*)d_in[2];     // [2,E]: src then dst
    const int*   bat = (const int*)d_in[3];
    const float* w1  = (const float*)d_in[4];
    const float* b1  = (const float*)d_in[5];
    const float* w2  = (const float*)d_in[6];
    const float* b2  = (const float*)d_in[7];
    const float* w3  = (const float*)d_in[8];
    const float* b3  = (const float*)d_in[9];
    const float* l1w = (const float*)d_in[10];
    const float* l1b = (const float*)d_in[11];
    const float* l2w = (const float*)d_in[12];
    const float* l2b = (const float*)d_in[13];
    float* out = (float*)d_out;

    const int N = in_sizes[0] / 128;   // 50000
    const int E = in_sizes[2] / 2;     // 800000
    const int NB = (N + 255) / 256;    // scan blocks (196)

    char* ws = (char*)d_ws;
    size_t off = 0;
    auto alloc = [&](size_t bytes) {
        void* p = ws + off;
        off = (off + bytes + 255) & ~(size_t)255;
        return p;
    };
    ushort* yb     = (ushort*)alloc((size_t)N * H * 2);   // bf16 messages
    float*  z      = (float*)alloc((size_t)N * H * 4);    // f32 aggregated
    int*    cnt    = (int*)alloc((size_t)N * 4);
    float*  dinv   = (float*)alloc((size_t)N * 4);
    int*    row_ptr= (int*)alloc((size_t)(N + 1) * 4);
    int*    fill   = (int*)alloc((size_t)N * 4);
    int*    ssrc   = (int*)alloc((size_t)E * 4);
    int*    bsum   = (int*)alloc(256 * 4);
    int*    boff   = (int*)alloc(256 * 4);
    float*  sums   = (float*)alloc((size_t)NG * H * 4);
    int*    gcnt   = (int*)alloc((size_t)NG * 4);

    hipMemsetAsync(cnt, 0, (size_t)N * 4, stream);
    hipMemsetAsync(sums, 0, (size_t)NG * H * 4, stream);
    hipMemsetAsync(gcnt, 0, (size_t)NG * 4, stream);

    hist_kernel<<<(E + 255) / 256, 256, 0, stream>>>(ei + E, cnt, E);
    dinv_kernel<<<(N + 255) / 256, 256, 0, stream>>>(cnt, dinv, N);
    scanA<<<NB, 256, 0, stream>>>(cnt, bsum, N);
    scanB<<<1, 256, 0, stream>>>(bsum, boff, row_ptr + N, NB);
    scanC<<<NB, 256, 0, stream>>>(cnt, boff, row_ptr, fill, N);
    scatter_kernel<<<(E + 255) / 256, 256, 0, stream>>>(ei, ei + E, fill, ssrc, E);

    // layer 1: aggregate x (width 128, bf16 messages) then GEMM 128->256
    prescale_kernel<<<(N * 128 / 4 + 255) / 256, 256, 0, stream>>>(x, dinv, yb, N * 128);
    agg_kernel<2><<<(N + 3) / 4, 256, 0, stream>>>(yb, dinv, row_ptr, ssrc, z, N);
    gemm_kernel<true><<<dim3((N + 63) / 64, 4), 256, 0, stream>>>(z, w1, b1, dinv, yb, N, 128);

    // layer 2
    agg_kernel<4><<<(N + 3) / 4, 256, 0, stream>>>(yb, dinv, row_ptr, ssrc, z, N);
    gemm_kernel<true><<<dim3((N + 63) / 64, 4), 256, 0, stream>>>(z, w2, b2, dinv, yb, N, 256);

    // layer 3: aggregate only; W3 folds into the head (pool commutes with linear, no relu)
    agg_kernel<4><<<(N + 3) / 4, 256, 0, stream>>>(yb, dinv, row_ptr, ssrc, z, N);

    pool_kernel<<<(N + 127) / 128, 256, 0, stream>>>(z, bat, sums, gcnt, N);
    head_kernel<<<NG, 256, 0, stream>>>(sums, gcnt, w3, b3, l1w, l1b, l2w, l2b, out);
}

// Round 6
// 485.979 us; speedup vs baseline: 1.6803x; 1.1395x over previous
//
#include <hip/hip_runtime.h>
#include <cstdint>

constexpr int NG = 64;     // graphs
constexpr int H  = 256;    // hidden width

typedef __bf16 bf16x8 __attribute__((ext_vector_type(8)));
typedef float  f32x4  __attribute__((ext_vector_type(4)));

// ---------- bf16 helpers (RNE pack, bit-shift unpack) ----------
__device__ __forceinline__ uint32_t pk_bf16(float a, float b) {
    uint32_t ua = __builtin_bit_cast(uint32_t, a);
    uint32_t ub = __builtin_bit_cast(uint32_t, b);
    ua += 0x7fffu + ((ua >> 16) & 1u);
    ub += 0x7fffu + ((ub >> 16) & 1u);
    return (ua >> 16) | (ub & 0xffff0000u);
}
__device__ __forceinline__ ushort bf16r(float x) {
    uint32_t u = __builtin_bit_cast(uint32_t, x);
    u += 0x7fffu + ((u >> 16) & 1u);
    return (ushort)(u >> 16);
}
__device__ __forceinline__ float bf2f(ushort h) {
    return __builtin_bit_cast(float, ((uint32_t)h) << 16);
}
__device__ __forceinline__ void bf2acc(uint32_t u, float& a0, float& a1) {
    a0 += __builtin_bit_cast(float, u << 16);
    a1 += __builtin_bit_cast(float, u & 0xffff0000u);
}

// ---------- degree histogram over real edges ----------
__global__ void hist_kernel(const int* __restrict__ dst, int* __restrict__ cnt, int E) {
    int e = blockIdx.x * blockDim.x + threadIdx.x;
    if (e < E) atomicAdd(&cnt[dst[e]], 1);
}

// dinv = rsqrt(in_deg + 1)   (self-loop included)
__global__ void dinv_kernel(const int* __restrict__ cnt, float* __restrict__ dinv, int n) {
    int i = blockIdx.x * blockDim.x + threadIdx.x;
    if (i < n) dinv[i] = rsqrtf((float)(cnt[i] + 1));
}

// ---------- hierarchical exclusive scan ----------
__global__ __launch_bounds__(256) void scanA(const int* __restrict__ cnt, int* __restrict__ bsum, int n) {
    __shared__ int sh[256];
    int t = threadIdx.x, i = blockIdx.x * 256 + t;
    sh[t] = (i < n) ? cnt[i] : 0;
    __syncthreads();
    for (int off = 128; off > 0; off >>= 1) {
        if (t < off) sh[t] += sh[t + off];
        __syncthreads();
    }
    if (t == 0) bsum[blockIdx.x] = sh[0];
}

__global__ __launch_bounds__(256) void scanB(const int* __restrict__ bsum, int* __restrict__ boff,
                                             int* __restrict__ total_out, int nb) {
    __shared__ int sh[256];
    int t = threadIdx.x;
    int v = (t < nb) ? bsum[t] : 0;
    sh[t] = v;
    __syncthreads();
    for (int off = 1; off < 256; off <<= 1) {
        int a = (t >= off) ? sh[t - off] : 0;
        __syncthreads();
        sh[t] += a;
        __syncthreads();
    }
    if (t < nb) boff[t] = sh[t] - v;
    if (t == nb - 1) *total_out = sh[t];
}

__global__ __launch_bounds__(256) void scanC(const int* __restrict__ cnt, const int* __restrict__ boff,
                                             int* __restrict__ row_ptr, int* __restrict__ fill, int n) {
    __shared__ int sh[256];
    int t = threadIdx.x, i = blockIdx.x * 256 + t;
    int v = (i < n) ? cnt[i] : 0;
    sh[t] = v;
    __syncthreads();
    for (int off = 1; off < 256; off <<= 1) {
        int a = (t >= off) ? sh[t - off] : 0;
        __syncthreads();
        sh[t] += a;
        __syncthreads();
    }
    if (i < n) {
        int excl = boff[blockIdx.x] + sh[t] - v;
        row_ptr[i] = excl;
        fill[i] = excl;
    }
}

// ---------- counting-sort edges by dst ----------
__global__ void scatter_kernel(const int* __restrict__ src, const int* __restrict__ dst,
                               int* __restrict__ fill, int* __restrict__ ssrc, int E) {
    int e = blockIdx.x * blockDim.x + threadIdx.x;
    if (e < E) {
        int pos = atomicAdd(&fill[dst[e]], 1);
        ssrc[pos] = src[e];
    }
}

// ---------- W [K][256] f32 -> WT hi/lo [256][K] bf16 (hi + residual) ----------
__global__ void wconv_kernel(const float* __restrict__ w, ushort* __restrict__ hi,
                             ushort* __restrict__ lo, int K) {
    int idx = blockIdx.x * 256 + threadIdx.x;
    if (idx >= K * 256) return;
    int k = idx >> 8, n = idx & 255;
    float v = w[idx];
    ushort h = bf16r(v);
    float r = v - bf2f(h);
    hi[n * K + k] = h;
    lo[n * K + k] = bf16r(r);
}

// ---------- y0 = bf16(dinv ⊙ x)  (width 128) ----------
__global__ void prescale_kernel(const float* __restrict__ x, const float* __restrict__ dinv,
                                ushort* __restrict__ y, int total) {
    int idx = blockIdx.x * blockDim.x + threadIdx.x;
    int f = idx * 4;
    if (f >= total) return;
    float dv = dinv[f >> 7];
    float4 v = *reinterpret_cast<const float4*>(x + f);
    uint2 o;
    o.x = pk_bf16(v.x * dv, v.y * dv);
    o.y = pk_bf16(v.z * dv, v.w * dv);
    *reinterpret_cast<uint2*>(y + f) = o;
}

// ---------- agg: z[i] = bf16(dinv[i]*(y[i] + sum y[src])); y,z bf16 ----------
template<int VEC>
__global__ __launch_bounds__(256) void agg_kernel(const ushort* __restrict__ y,
                                                  const float* __restrict__ dinv,
                                                  const int* __restrict__ row_ptr,
                                                  const int* __restrict__ ssrc,
                                                  ushort* __restrict__ zout, int n) {
    constexpr int W = VEC * 64;
    int wave = threadIdx.x >> 6;
    int lane = threadIdx.x & 63;
    int node = blockIdx.x * 4 + wave;
    if (node >= n) return;
    float acc[VEC] = {};

    auto ld4 = [&](int s) -> uint2 {
        return *reinterpret_cast<const uint2*>(y + (size_t)s * W + lane * VEC);
    };
    auto ld2 = [&](int s) -> uint32_t {
        return *reinterpret_cast<const uint32_t*>(y + (size_t)s * W + lane * VEC);
    };

    if constexpr (VEC == 4) {
        uint2 v = ld4(node);
        bf2acc(v.x, acc[0], acc[1]); bf2acc(v.y, acc[2], acc[3]);
    } else {
        bf2acc(ld2(node), acc[0], acc[1]);
    }

    int beg = row_ptr[node], end = row_ptr[node + 1];
    int e = beg;
    for (; e + 4 <= end; e += 4) {
        int s0 = ssrc[e], s1 = ssrc[e + 1], s2 = ssrc[e + 2], s3 = ssrc[e + 3];
        if constexpr (VEC == 4) {
            uint2 v0 = ld4(s0), v1 = ld4(s1), v2 = ld4(s2), v3 = ld4(s3);
            bf2acc(v0.x, acc[0], acc[1]); bf2acc(v0.y, acc[2], acc[3]);
            bf2acc(v1.x, acc[0], acc[1]); bf2acc(v1.y, acc[2], acc[3]);
            bf2acc(v2.x, acc[0], acc[1]); bf2acc(v2.y, acc[2], acc[3]);
            bf2acc(v3.x, acc[0], acc[1]); bf2acc(v3.y, acc[2], acc[3]);
        } else {
            uint32_t v0 = ld2(s0), v1 = ld2(s1), v2 = ld2(s2), v3 = ld2(s3);
            bf2acc(v0, acc[0], acc[1]); bf2acc(v1, acc[0], acc[1]);
            bf2acc(v2, acc[0], acc[1]); bf2acc(v3, acc[0], acc[1]);
        }
    }
    for (; e < end; ++e) {
        if constexpr (VEC == 4) {
            uint2 v = ld4(ssrc[e]);
            bf2acc(v.x, acc[0], acc[1]); bf2acc(v.y, acc[2], acc[3]);
        } else {
            bf2acc(ld2(ssrc[e]), acc[0], acc[1]);
        }
    }

    float dv = dinv[node];
    ushort* zp = zout + (size_t)node * W + lane * VEC;
    if constexpr (VEC == 4) {
        uint2 o;
        o.x = pk_bf16(dv * acc[0], dv * acc[1]);
        o.y = pk_bf16(dv * acc[2], dv * acc[3]);
        *reinterpret_cast<uint2*>(zp) = o;
    } else {
        *reinterpret_cast<uint32_t*>(zp) = pk_bf16(dv * acc[0], dv * acc[1]);
    }
}

// ---------- MFMA GEMM: C = bf16(dinv ⊙ relu(A@(Whi+Wlo) + b)) ----------
// A: [M][K] bf16, Bhi/Blo: [256][K] bf16 (n-major), C: [M][256] bf16
template<bool RELU>
__global__ __launch_bounds__(256) void mfma_gemm(const ushort* __restrict__ A,
                                                 const ushort* __restrict__ Bhi,
                                                 const ushort* __restrict__ Blo,
                                                 const float* __restrict__ bias,
                                                 const float* __restrict__ dinv,
                                                 ushort* __restrict__ C, int M, int K) {
    constexpr int BM = 64, BN = 64, BK = 64;
    constexpr int LDK = BK + 8;    // 72 ushorts = 144 B/row = 9*16B -> b128-aligned rows
    __shared__ ushort As[BM][LDK];
    __shared__ ushort Bh[BN][LDK];
    __shared__ ushort Bl[BN][LDK];

    const int tid = threadIdx.x;
    const int w = tid >> 6;        // wave 0..3 -> owns 16-col strip
    const int l = tid & 63;
    const int lr = l & 15;         // row/col within fragment
    const int lk = (l >> 4) * 8;   // k-offset of this lane's 8 contiguous elements
    const int bm = blockIdx.x * BM;
    const int bn = blockIdx.y * BN;

    f32x4 acc[4];
    #pragma unroll
    for (int i = 0; i < 4; ++i) acc[i] = (f32x4){0.f, 0.f, 0.f, 0.f};

    for (int k0 = 0; k0 < K; k0 += BK) {
        // stage 64x64 bf16 tiles: 512 slots x 8 bf16 (uint4 = 16B)  [r5 fix: was uint2]
        #pragma unroll
        for (int p = 0; p < 2; ++p) {
            int g = tid + p * 256;
            int r = g >> 3;
            int c = (g & 7) << 3;
            int grow = bm + r;
            uint4 va = make_uint4(0u, 0u, 0u, 0u);
            if (grow < M) va = *reinterpret_cast<const uint4*>(A + (size_t)grow * K + k0 + c);
            *reinterpret_cast<uint4*>(&As[r][c]) = va;
            *reinterpret_cast<uint4*>(&Bh[r][c]) =
                *reinterpret_cast<const uint4*>(Bhi + (size_t)(bn + r) * K + k0 + c);
            *reinterpret_cast<uint4*>(&Bl[r][c]) =
                *reinterpret_cast<const uint4*>(Blo + (size_t)(bn + r) * K + k0 + c);
        }
        __syncthreads();
        #pragma unroll
        for (int kk = 0; kk < BK; kk += 32) {
            bf16x8 bh = *reinterpret_cast<const bf16x8*>(&Bh[w * 16 + lr][kk + lk]);
            bf16x8 bl = *reinterpret_cast<const bf16x8*>(&Bl[w * 16 + lr][kk + lk]);
            #pragma unroll
            for (int r16 = 0; r16 < 4; ++r16) {
                bf16x8 a = *reinterpret_cast<const bf16x8*>(&As[r16 * 16 + lr][kk + lk]);
                acc[r16] = __builtin_amdgcn_mfma_f32_16x16x32_bf16(a, bh, acc[r16], 0, 0, 0);
                acc[r16] = __builtin_amdgcn_mfma_f32_16x16x32_bf16(a, bl, acc[r16], 0, 0, 0);
            }
        }
        __syncthreads();
    }

    // epilogue: C row = bm + r16*16 + (l>>4)*4 + j, col = bn + w*16 + lr
    int col = bn + w * 16 + lr;
    float bv = bias[col];
    #pragma unroll
    for (int r16 = 0; r16 < 4; ++r16) {
        #pragma unroll
        for (int j = 0; j < 4; ++j) {
            int row = bm + r16 * 16 + (l >> 4) * 4 + j;
            if (row < M) {
                float v = acc[r16][j] + bv;
                if (RELU) v = fmaxf(v, 0.f);
                v *= dinv[row];
                C[(size_t)row * H + col] = bf16r(v);
            }
        }
    }
}

// ---------- mean-pool partials over bf16 rows: batch sorted, flush at boundaries ----------
__global__ __launch_bounds__(256) void pool_kernel(const ushort* __restrict__ z,
                                                   const int* __restrict__ batch,
                                                   float* __restrict__ sums,
                                                   int* __restrict__ gcnt, int n) {
    constexpr int NCH = 128;
    int t = threadIdx.x;
    int base = blockIdx.x * NCH;
    if (base >= n) return;
    int endn = min(base + NCH, n);
    int cur = batch[base];
    float local = 0.f;
    int cl = 0;
    for (int i = base; i < endn; ++i) {
        int g = batch[i];
        if (g != cur) {
            atomicAdd(&sums[cur * H + t], local);
            if (t == 0) atomicAdd(&gcnt[cur], cl);
            local = 0.f; cl = 0; cur = g;
        }
        local += bf2f(z[(size_t)i * H + t]);
        cl++;
    }
    atomicAdd(&sums[cur * H + t], local);
    if (t == 0) atomicAdd(&gcnt[cur], cl);
}

// ---------- head ----------
__global__ __launch_bounds__(256) void head_kernel(const float* __restrict__ sums,
                                                   const int* __restrict__ gcnt,
                                                   const float* __restrict__ w3, const float* __restrict__ b3,
                                                   const float* __restrict__ l1w, const float* __restrict__ l1b,
                                                   const float* __restrict__ l2w, const float* __restrict__ l2b,
                                                   float* __restrict__ out) {
    __shared__ float pooled[H];
    __shared__ float t3[H];
    __shared__ float mid[H / 2];
    int g = blockIdx.x, t = threadIdx.x;
    float c = (float)max(gcnt[g], 1);
    pooled[t] = sums[g * H + t] / c;
    __syncthreads();
    float a = b3[t];
    for (int k = 0; k < H; ++k) a += pooled[k] * w3[k * H + t];
    t3[t] = a;
    __syncthreads();
    if (t < H / 2) {
        float m = l1b[t];
        for (int k = 0; k < H; ++k) m += t3[k] * l1w[k * (H / 2) + t];
        mid[t] = m;
    }
    __syncthreads();
    if (t < 3) {
        float o = l2b[t];
        for (int k = 0; k < H / 2; ++k) o += mid[k] * l2w[k * 3 + t];
        out[g * 3 + t] = o;
    }
}

extern "C" void kernel_launch(void* const* d_in, const int* in_sizes, int n_in,
                              void* d_out, int out_size, void* d_ws, size_t ws_size,
                              hipStream_t stream) {
    const float* x   = (const float*)d_in[0];
    const int*   ei  = (const int*)d_in[2];
    const int*   bat = (const int*)d_in[3];
    const float* w1  = (const float*)d_in[4];
    const float* b1  = (const float*)d_in[5];
    const float* w2  = (const float*)d_in[6];
    const float* b2  = (const float*)d_in[7];
    const float* w3  = (const float*)d_in[8];
    const float* b3  = (const float*)d_in[9];
    const float* l1w = (const float*)d_in[10];
    const float* l1b = (const float*)d_in[11];
    const float* l2w = (const float*)d_in[12];
    const float* l2b = (const float*)d_in[13];
    float* out = (float*)d_out;

    const int N = in_sizes[0] / 128;   // 50000
    const int E = in_sizes[2] / 2;     // 800000
    const int NB = (N + 255) / 256;

    char* ws = (char*)d_ws;
    size_t off = 0;
    auto alloc = [&](size_t bytes) {
        void* p = ws + off;
        off = (off + bytes + 255) & ~(size_t)255;
        return p;
    };
    // total footprint ~56MB
    ushort* yb     = (ushort*)alloc((size_t)N * H * 2);   // bf16 ping
    ushort* z16    = (ushort*)alloc((size_t)N * H * 2);   // bf16 pong
    int*    cnt    = (int*)alloc((size_t)N * 4);
    float*  dinv   = (float*)alloc((size_t)N * 4);
    int*    row_ptr= (int*)alloc((size_t)(N + 1) * 4);
    int*    fill   = (int*)alloc((size_t)N * 4);
    int*    ssrc   = (int*)alloc((size_t)E * 4);
    int*    bsum   = (int*)alloc(256 * 4);
    int*    boff   = (int*)alloc(256 * 4);
    ushort* wt1h   = (ushort*)alloc((size_t)128 * 256 * 2);
    ushort* wt1l   = (ushort*)alloc((size_t)128 * 256 * 2);
    ushort* wt2h   = (ushort*)alloc((size_t)256 * 256 * 2);
    ushort* wt2l   = (ushort*)alloc((size_t)256 * 256 * 2);
    float*  sums   = (float*)alloc((size_t)NG * H * 4);
    int*    gcnt   = (int*)alloc((size_t)NG * 4);

    hipMemsetAsync(cnt, 0, (size_t)N * 4, stream);
    hipMemsetAsync(sums, 0, (size_t)NG * H * 4, stream);
    hipMemsetAsync(gcnt, 0, (size_t)NG * 4, stream);

    hist_kernel<<<(E + 255) / 256, 256, 0, stream>>>(ei + E, cnt, E);
    dinv_kernel<<<(N + 255) / 256, 256, 0, stream>>>(cnt, dinv, N);
    scanA<<<NB, 256, 0, stream>>>(cnt, bsum, N);
    scanB<<<1, 256, 0, stream>>>(bsum, boff, row_ptr + N, NB);
    scanC<<<NB, 256, 0, stream>>>(cnt, boff, row_ptr, fill, N);
    scatter_kernel<<<(E + 255) / 256, 256, 0, stream>>>(ei, ei + E, fill, ssrc, E);

    wconv_kernel<<<(128 * 256) / 256, 256, 0, stream>>>(w1, wt1h, wt1l, 128);
    wconv_kernel<<<(256 * 256) / 256, 256, 0, stream>>>(w2, wt2h, wt2l, 256);

    // layer 1: aggregate x (width 128) -> bf16, MFMA GEMM 128->256
    prescale_kernel<<<(N * 128 / 4 + 255) / 256, 256, 0, stream>>>(x, dinv, yb, N * 128);
    agg_kernel<2><<<(N + 3) / 4, 256, 0, stream>>>(yb, dinv, row_ptr, ssrc, z16, N);
    mfma_gemm<true><<<dim3((N + 63) / 64, 4), 256, 0, stream>>>(z16, wt1h, wt1l, b1, dinv, yb, N, 128);

    // layer 2
    agg_kernel<4><<<(N + 3) / 4, 256, 0, stream>>>(yb, dinv, row_ptr, ssrc, z16, N);
    mfma_gemm<true><<<dim3((N + 63) / 64, 4), 256, 0, stream>>>(z16, wt2h, wt2l, b2, dinv, yb, N, 256);

    // layer 3: aggregate only (W3 folded into head), bf16 out
    agg_kernel<4><<<(N + 3) / 4, 256, 0, stream>>>(yb, dinv, row_ptr, ssrc, z16, N);

    pool_kernel<<<(N + 127) / 128, 256, 0, stream>>>(z16, bat, sums, gcnt, N);
    head_kernel<<<NG, 256, 0, stream>>>(sums, gcnt, w3, b3, l1w, l1b, l2w, l2b, out);
}

// Round 7
// 470.036 us; speedup vs baseline: 1.7373x; 1.0339x over previous
//
#include <hip/hip_runtime.h>
#include <cstdint>

constexpr int NG = 64;     // graphs
constexpr int H  = 256;    // hidden width

typedef __bf16 bf16x8 __attribute__((ext_vector_type(8)));
typedef float  f32x4  __attribute__((ext_vector_type(4)));

// ---------- bf16 helpers (RNE pack, bit-shift unpack) ----------
__device__ __forceinline__ uint32_t pk_bf16(float a, float b) {
    uint32_t ua = __builtin_bit_cast(uint32_t, a);
    uint32_t ub = __builtin_bit_cast(uint32_t, b);
    ua += 0x7fffu + ((ua >> 16) & 1u);
    ub += 0x7fffu + ((ub >> 16) & 1u);
    return (ua >> 16) | (ub & 0xffff0000u);
}
__device__ __forceinline__ ushort bf16r(float x) {
    uint32_t u = __builtin_bit_cast(uint32_t, x);
    u += 0x7fffu + ((u >> 16) & 1u);
    return (ushort)(u >> 16);
}
__device__ __forceinline__ float bf2f(ushort h) {
    return __builtin_bit_cast(float, ((uint32_t)h) << 16);
}
__device__ __forceinline__ void bf2acc(uint32_t u, float& a0, float& a1) {
    a0 += __builtin_bit_cast(float, u << 16);
    a1 += __builtin_bit_cast(float, u & 0xffff0000u);
}

// ---------- degree histogram over real edges ----------
__global__ void hist_kernel(const int* __restrict__ dst, int* __restrict__ cnt, int E) {
    int e = blockIdx.x * blockDim.x + threadIdx.x;
    if (e < E) atomicAdd(&cnt[dst[e]], 1);
}

// ---------- scanA + dinv fused: block sums and dinv = rsqrt(cnt+1) ----------
__global__ __launch_bounds__(256) void scanA(const int* __restrict__ cnt, int* __restrict__ bsum,
                                             float* __restrict__ dinv, int n) {
    __shared__ int sh[256];
    int t = threadIdx.x, i = blockIdx.x * 256 + t;
    int v = (i < n) ? cnt[i] : 0;
    if (i < n) dinv[i] = rsqrtf((float)(v + 1));
    sh[t] = v;
    __syncthreads();
    for (int off = 128; off > 0; off >>= 1) {
        if (t < off) sh[t] += sh[t + off];
        __syncthreads();
    }
    if (t == 0) bsum[blockIdx.x] = sh[0];
}

__global__ __launch_bounds__(256) void scanB(const int* __restrict__ bsum, int* __restrict__ boff,
                                             int* __restrict__ total_out, int nb) {
    __shared__ int sh[256];
    int t = threadIdx.x;
    int v = (t < nb) ? bsum[t] : 0;
    sh[t] = v;
    __syncthreads();
    for (int off = 1; off < 256; off <<= 1) {
        int a = (t >= off) ? sh[t - off] : 0;
        __syncthreads();
        sh[t] += a;
        __syncthreads();
    }
    if (t < nb) boff[t] = sh[t] - v;
    if (t == nb - 1) *total_out = sh[t];
}

__global__ __launch_bounds__(256) void scanC(const int* __restrict__ cnt, const int* __restrict__ boff,
                                             int* __restrict__ row_ptr, int* __restrict__ fill, int n) {
    __shared__ int sh[256];
    int t = threadIdx.x, i = blockIdx.x * 256 + t;
    int v = (i < n) ? cnt[i] : 0;
    sh[t] = v;
    __syncthreads();
    for (int off = 1; off < 256; off <<= 1) {
        int a = (t >= off) ? sh[t - off] : 0;
        __syncthreads();
        sh[t] += a;
        __syncthreads();
    }
    if (i < n) {
        int excl = boff[blockIdx.x] + sh[t] - v;
        row_ptr[i] = excl;
        fill[i] = excl;
    }
}

// ---------- fused: counting-sort scatter + prescale y0 = bf16(dinv ⊙ x) ----------
__global__ void sp_kernel(const int* __restrict__ src, const int* __restrict__ dst,
                          int* __restrict__ fill, int* __restrict__ ssrc, int E,
                          const float* __restrict__ x, const float* __restrict__ dinv,
                          ushort* __restrict__ y, int np4 /* N*128/4 */) {
    int i = blockIdx.x * blockDim.x + threadIdx.x;
    if (i < E) {
        int pos = atomicAdd(&fill[dst[i]], 1);
        ssrc[pos] = src[i];
    }
    if (i < np4) {
        int f = i * 4;
        float dv = dinv[f >> 7];
        float4 v = *reinterpret_cast<const float4*>(x + f);
        uint2 o;
        o.x = pk_bf16(v.x * dv, v.y * dv);
        o.y = pk_bf16(v.z * dv, v.w * dv);
        *reinterpret_cast<uint2*>(y + f) = o;
    }
}

// ---------- both W [K][256] f32 -> WT hi/lo [256][K] bf16 (hi + residual) ----------
__global__ void wconv_kernel(const float* __restrict__ w1, ushort* __restrict__ h1, ushort* __restrict__ l1,
                             const float* __restrict__ w2, ushort* __restrict__ h2, ushort* __restrict__ l2) {
    int idx = blockIdx.x * 256 + threadIdx.x;
    const float* w; ushort *hi, *lo; int K;
    if (idx < 128 * 256) { w = w1; hi = h1; lo = l1; K = 128; }
    else { idx -= 128 * 256; if (idx >= 256 * 256) return; w = w2; hi = h2; lo = l2; K = 256; }
    int k = idx / 256, n = idx & 255;
    float v = w[idx];
    ushort h = bf16r(v);
    float r = v - bf2f(h);
    hi[n * K + k] = h;
    lo[n * K + k] = bf16r(r);
}

// ---------- agg: z[i] = bf16(dinv[i]*(y[i] + sum y[src])); 8-deep gather pipeline ----------
template<int VEC>
__global__ __launch_bounds__(256) void agg_kernel(const ushort* __restrict__ y,
                                                  const float* __restrict__ dinv,
                                                  const int* __restrict__ row_ptr,
                                                  const int* __restrict__ ssrc,
                                                  ushort* __restrict__ zout, int n) {
    constexpr int W = VEC * 64;
    int wave = threadIdx.x >> 6;
    int lane = threadIdx.x & 63;
    int node = blockIdx.x * 4 + wave;
    if (node >= n) return;
    float acc[VEC] = {};

    auto ld4 = [&](int s) -> uint2 {
        return *reinterpret_cast<const uint2*>(y + (size_t)s * W + lane * VEC);
    };
    auto ld2 = [&](int s) -> uint32_t {
        return *reinterpret_cast<const uint32_t*>(y + (size_t)s * W + lane * VEC);
    };

    if constexpr (VEC == 4) {
        uint2 v = ld4(node);
        bf2acc(v.x, acc[0], acc[1]); bf2acc(v.y, acc[2], acc[3]);
    } else {
        bf2acc(ld2(node), acc[0], acc[1]);
    }

    int beg = row_ptr[node], end = row_ptr[node + 1];
    int e = beg;
    // 8-deep: issue 8 independent row gathers before accumulating
    for (; e + 8 <= end; e += 8) {
        int s[8];
        #pragma unroll
        for (int q = 0; q < 8; ++q) s[q] = ssrc[e + q];
        if constexpr (VEC == 4) {
            uint2 v[8];
            #pragma unroll
            for (int q = 0; q < 8; ++q) v[q] = ld4(s[q]);
            #pragma unroll
            for (int q = 0; q < 8; ++q) {
                bf2acc(v[q].x, acc[0], acc[1]); bf2acc(v[q].y, acc[2], acc[3]);
            }
        } else {
            uint32_t v[8];
            #pragma unroll
            for (int q = 0; q < 8; ++q) v[q] = ld2(s[q]);
            #pragma unroll
            for (int q = 0; q < 8; ++q) bf2acc(v[q], acc[0], acc[1]);
        }
    }
    for (; e + 4 <= end; e += 4) {
        int s[4];
        #pragma unroll
        for (int q = 0; q < 4; ++q) s[q] = ssrc[e + q];
        if constexpr (VEC == 4) {
            uint2 v[4];
            #pragma unroll
            for (int q = 0; q < 4; ++q) v[q] = ld4(s[q]);
            #pragma unroll
            for (int q = 0; q < 4; ++q) {
                bf2acc(v[q].x, acc[0], acc[1]); bf2acc(v[q].y, acc[2], acc[3]);
            }
        } else {
            uint32_t v[4];
            #pragma unroll
            for (int q = 0; q < 4; ++q) v[q] = ld2(s[q]);
            #pragma unroll
            for (int q = 0; q < 4; ++q) bf2acc(v[q], acc[0], acc[1]);
        }
    }
    for (; e < end; ++e) {
        if constexpr (VEC == 4) {
            uint2 v = ld4(ssrc[e]);
            bf2acc(v.x, acc[0], acc[1]); bf2acc(v.y, acc[2], acc[3]);
        } else {
            bf2acc(ld2(ssrc[e]), acc[0], acc[1]);
        }
    }

    float dv = dinv[node];
    ushort* zp = zout + (size_t)node * W + lane * VEC;
    if constexpr (VEC == 4) {
        uint2 o;
        o.x = pk_bf16(dv * acc[0], dv * acc[1]);
        o.y = pk_bf16(dv * acc[2], dv * acc[3]);
        *reinterpret_cast<uint2*>(zp) = o;
    } else {
        *reinterpret_cast<uint32_t*>(zp) = pk_bf16(dv * acc[0], dv * acc[1]);
    }
}

// ---------- MFMA GEMM: C = bf16(dinv ⊙ relu(A@(Whi+Wlo) + b)) ----------
// A: [M][K] bf16, Bhi/Blo: [256][K] bf16 (n-major), C: [M][256] bf16
// 128x64 tile, 4 waves each owning a 128x16 strip (8 acc frags)
template<bool RELU>
__global__ __launch_bounds__(256) void mfma_gemm(const ushort* __restrict__ A,
                                                 const ushort* __restrict__ Bhi,
                                                 const ushort* __restrict__ Blo,
                                                 const float* __restrict__ bias,
                                                 const float* __restrict__ dinv,
                                                 ushort* __restrict__ C, int M, int K) {
    constexpr int BM = 128, BN = 64, BK = 64;
    constexpr int LDK = BK + 8;    // 72 ushorts = 144 B/row -> rows stay 16B aligned
    __shared__ ushort As[BM][LDK];   // 18 KB
    __shared__ ushort Bh[BN][LDK];   // 9 KB
    __shared__ ushort Bl[BN][LDK];   // 9 KB

    const int tid = threadIdx.x;
    const int w = tid >> 6;        // wave 0..3 -> 16-col strip
    const int l = tid & 63;
    const int lr = l & 15;
    const int lk = (l >> 4) * 8;
    const int bm = blockIdx.x * BM;
    const int bn = blockIdx.y * BN;

    f32x4 acc[8];
    #pragma unroll
    for (int i = 0; i < 8; ++i) acc[i] = (f32x4){0.f, 0.f, 0.f, 0.f};

    for (int k0 = 0; k0 < K; k0 += BK) {
        #pragma unroll
        for (int p = 0; p < 4; ++p) {           // A: 1024 slots x 8 bf16
            int g = tid + p * 256;
            int r = g >> 3;
            int c = (g & 7) << 3;
            int grow = bm + r;
            uint4 va = make_uint4(0u, 0u, 0u, 0u);
            if (grow < M) va = *reinterpret_cast<const uint4*>(A + (size_t)grow * K + k0 + c);
            *reinterpret_cast<uint4*>(&As[r][c]) = va;
        }
        #pragma unroll
        for (int p = 0; p < 2; ++p) {           // B hi/lo: 512 slots each
            int g = tid + p * 256;
            int r = g >> 3;
            int c = (g & 7) << 3;
            *reinterpret_cast<uint4*>(&Bh[r][c]) =
                *reinterpret_cast<const uint4*>(Bhi + (size_t)(bn + r) * K + k0 + c);
            *reinterpret_cast<uint4*>(&Bl[r][c]) =
                *reinterpret_cast<const uint4*>(Blo + (size_t)(bn + r) * K + k0 + c);
        }
        __syncthreads();
        #pragma unroll
        for (int kk = 0; kk < BK; kk += 32) {
            bf16x8 bh = *reinterpret_cast<const bf16x8*>(&Bh[w * 16 + lr][kk + lk]);
            bf16x8 bl = *reinterpret_cast<const bf16x8*>(&Bl[w * 16 + lr][kk + lk]);
            #pragma unroll
            for (int r16 = 0; r16 < 8; ++r16) {
                bf16x8 a = *reinterpret_cast<const bf16x8*>(&As[r16 * 16 + lr][kk + lk]);
                acc[r16] = __builtin_amdgcn_mfma_f32_16x16x32_bf16(a, bh, acc[r16], 0, 0, 0);
                acc[r16] = __builtin_amdgcn_mfma_f32_16x16x32_bf16(a, bl, acc[r16], 0, 0, 0);
            }
        }
        __syncthreads();
    }

    int col = bn + w * 16 + lr;
    float bv = bias[col];
    #pragma unroll
    for (int r16 = 0; r16 < 8; ++r16) {
        #pragma unroll
        for (int j = 0; j < 4; ++j) {
            int row = bm + r16 * 16 + (l >> 4) * 4 + j;
            if (row < M) {
                float v = acc[r16][j] + bv;
                if (RELU) v = fmaxf(v, 0.f);
                v *= dinv[row];
                C[(size_t)row * H + col] = bf16r(v);
            }
        }
    }
}

// ---------- mean-pool partials over bf16 rows: batch sorted, flush at boundaries ----------
__global__ __launch_bounds__(256) void pool_kernel(const ushort* __restrict__ z,
                                                   const int* __restrict__ batch,
                                                   float* __restrict__ sums,
                                                   int* __restrict__ gcnt, int n) {
    constexpr int NCH = 128;
    int t = threadIdx.x;
    int base = blockIdx.x * NCH;
    if (base >= n) return;
    int endn = min(base + NCH, n);
    int cur = batch[base];
    float local = 0.f;
    int cl = 0;
    for (int i = base; i < endn; ++i) {
        int g = batch[i];
        if (g != cur) {
            atomicAdd(&sums[cur * H + t], local);
            if (t == 0) atomicAdd(&gcnt[cur], cl);
            local = 0.f; cl = 0; cur = g;
        }
        local += bf2f(z[(size_t)i * H + t]);
        cl++;
    }
    atomicAdd(&sums[cur * H + t], local);
    if (t == 0) atomicAdd(&gcnt[cur], cl);
}

// ---------- head ----------
__global__ __launch_bounds__(256) void head_kernel(const float* __restrict__ sums,
                                                   const int* __restrict__ gcnt,
                                                   const float* __restrict__ w3, const float* __restrict__ b3,
                                                   const float* __restrict__ l1w, const float* __restrict__ l1b,
                                                   const float* __restrict__ l2w, const float* __restrict__ l2b,
                                                   float* __restrict__ out) {
    __shared__ float pooled[H];
    __shared__ float t3[H];
    __shared__ float mid[H / 2];
    int g = blockIdx.x, t = threadIdx.x;
    float c = (float)max(gcnt[g], 1);
    pooled[t] = sums[g * H + t] / c;
    __syncthreads();
    float a = b3[t];
    for (int k = 0; k < H; ++k) a += pooled[k] * w3[k * H + t];
    t3[t] = a;
    __syncthreads();
    if (t < H / 2) {
        float m = l1b[t];
        for (int k = 0; k < H; ++k) m += t3[k] * l1w[k * (H / 2) + t];
        mid[t] = m;
    }
    __syncthreads();
    if (t < 3) {
        float o = l2b[t];
        for (int k = 0; k < H / 2; ++k) o += mid[k] * l2w[k * 3 + t];
        out[g * 3 + t] = o;
    }
}

extern "C" void kernel_launch(void* const* d_in, const int* in_sizes, int n_in,
                              void* d_out, int out_size, void* d_ws, size_t ws_size,
                              hipStream_t stream) {
    const float* x   = (const float*)d_in[0];
    const int*   ei  = (const int*)d_in[2];
    const int*   bat = (const int*)d_in[3];
    const float* w1  = (const float*)d_in[4];
    const float* b1  = (const float*)d_in[5];
    const float* w2  = (const float*)d_in[6];
    const float* b2  = (const float*)d_in[7];
    const float* w3  = (const float*)d_in[8];
    const float* b3  = (const float*)d_in[9];
    const float* l1w = (const float*)d_in[10];
    const float* l1b = (const float*)d_in[11];
    const float* l2w = (const float*)d_in[12];
    const float* l2b = (const float*)d_in[13];
    float* out = (float*)d_out;

    const int N = in_sizes[0] / 128;   // 50000
    const int E = in_sizes[2] / 2;     // 800000
    const int NB = (N + 255) / 256;

    char* ws = (char*)d_ws;
    size_t off = 0;
    auto alloc = [&](size_t bytes) {
        void* p = ws + off;
        off = (off + bytes + 255) & ~(size_t)255;
        return p;
    };
    ushort* yb     = (ushort*)alloc((size_t)N * H * 2);   // bf16 ping
    ushort* z16    = (ushort*)alloc((size_t)N * H * 2);   // bf16 pong
    int*    cnt    = (int*)alloc((size_t)N * 4);
    float*  dinv   = (float*)alloc((size_t)N * 4);
    int*    row_ptr= (int*)alloc((size_t)(N + 1) * 4);
    int*    fill   = (int*)alloc((size_t)N * 4);
    int*    ssrc   = (int*)alloc((size_t)E * 4);
    int*    bsum   = (int*)alloc(256 * 4);
    int*    boff   = (int*)alloc(256 * 4);
    ushort* wt1h   = (ushort*)alloc((size_t)128 * 256 * 2);
    ushort* wt1l   = (ushort*)alloc((size_t)128 * 256 * 2);
    ushort* wt2h   = (ushort*)alloc((size_t)256 * 256 * 2);
    ushort* wt2l   = (ushort*)alloc((size_t)256 * 256 * 2);
    float*  sums   = (float*)alloc((size_t)NG * H * 4);
    int*    gcnt   = (int*)alloc((size_t)NG * 4);

    hipMemsetAsync(cnt, 0, (size_t)N * 4, stream);
    hipMemsetAsync(sums, 0, (size_t)NG * H * 4, stream);
    hipMemsetAsync(gcnt, 0, (size_t)NG * 4, stream);

    hist_kernel<<<(E + 255) / 256, 256, 0, stream>>>(ei + E, cnt, E);
    scanA<<<NB, 256, 0, stream>>>(cnt, bsum, dinv, N);
    scanB<<<1, 256, 0, stream>>>(bsum, boff, row_ptr + N, NB);
    scanC<<<NB, 256, 0, stream>>>(cnt, boff, row_ptr, fill, N);
    wconv_kernel<<<(128 * 256 + 256 * 256) / 256, 256, 0, stream>>>(w1, wt1h, wt1l, w2, wt2h, wt2l);
    // fused scatter + prescale (both only need scanC / scanA results)
    sp_kernel<<<(N * 32 + 255) / 256, 256, 0, stream>>>(ei, ei + E, fill, ssrc, E,
                                                        x, dinv, yb, N * 32);

    // layer 1: aggregate x (width 128) -> bf16, MFMA GEMM 128->256
    agg_kernel<2><<<(N + 3) / 4, 256, 0, stream>>>(yb, dinv, row_ptr, ssrc, z16, N);
    mfma_gemm<true><<<dim3((N + 127) / 128, 4), 256, 0, stream>>>(z16, wt1h, wt1l, b1, dinv, yb, N, 128);

    // layer 2
    agg_kernel<4><<<(N + 3) / 4, 256, 0, stream>>>(yb, dinv, row_ptr, ssrc, z16, N);
    mfma_gemm<true><<<dim3((N + 127) / 128, 4), 256, 0, stream>>>(z16, wt2h, wt2l, b2, dinv, yb, N, 256);

    // layer 3: aggregate only (W3 folded into head), bf16 out
    agg_kernel<4><<<(N + 3) / 4, 256, 0, stream>>>(yb, dinv, row_ptr, ssrc, z16, N);

    pool_kernel<<<(N + 127) / 128, 256, 0, stream>>>(z16, bat, sums, gcnt, N);
    head_kernel<<<NG, 256, 0, stream>>>(sums, gcnt, w3, b3, l1w, l1b, l2w, l2b, out);
}